// Round 9
// baseline (80.667 us; speedup 1.0000x reference)
//
#include <hip/hip_runtime.h>

#define N   2048
#define NT  128
#define EPK 16  // 2 waves per problem: 2*64*16 = 2048

typedef unsigned int u32;

// monotone float->uint key: ascending uint order == ascending float order
__device__ __forceinline__ u32 fkey(float f) {
  u32 u = __float_as_uint(f);
  return (u & 0x80000000u) ? ~u : (u | 0x80000000u);
}

__device__ __forceinline__ u32 umin32(u32 a, u32 b) { return a < b ? a : b; }
__device__ __forceinline__ u32 umax32(u32 a, u32 b) { return a < b ? b : a; }

// lane-xor exchange of a u32, cheapest available unit per distance:
//   xor1/xor2: DPP quad_perm (VALU)   xor8: DPP row_ror:8 (rot 8 within 16 == xor8)
//   xor4/xor16: ds_swizzle BitMode    xor32: v_permlane32_swap (gfx950 VALU)
template <int D>
__device__ __forceinline__ u32 exch(u32 x, int lane) {
  if constexpr (D == 1) {
    return (u32)__builtin_amdgcn_update_dpp((int)x, (int)x, 0xB1, 0xF, 0xF, true);
  } else if constexpr (D == 2) {
    return (u32)__builtin_amdgcn_update_dpp((int)x, (int)x, 0x4E, 0xF, 0xF, true);
  } else if constexpr (D == 4) {
    return (u32)__builtin_amdgcn_ds_swizzle((int)x, 0x101F);  // (lane&31)^4
  } else if constexpr (D == 8) {
    return (u32)__builtin_amdgcn_update_dpp((int)x, (int)x, 0x128, 0xF, 0xF, true);
  } else if constexpr (D == 16) {
    return (u32)__builtin_amdgcn_ds_swizzle((int)x, 0x401F);  // (lane&31)^16
  } else {  // D == 32
    int a = (int)x, b = (int)x;
    asm("v_permlane32_swap_b32 %0, %1" : "+v"(a), "+v"(b));
    return (lane & 32) ? (u32)a : (u32)b;
  }
}

// one bitonic pass at lane-distance D (element distance 16*D)
template <int D>
__device__ __forceinline__ void sh_pass(u32* kv, bool keep_min, int lane) {
#pragma unroll
  for (int m = 0; m < EPK; ++m) {
    u32 o = exch<D>(kv[m], lane);
    u32 mn = umin32(kv[m], o), mx = umax32(kv[m], o);
    kv[m] = keep_min ? mn : mx;
  }
}

// in-lane pass at element distance J (<=8)
#define INPASS(J, UPEXPR)                               \
  {                                                     \
    _Pragma("unroll")                                   \
    for (int m = 0; m < EPK; ++m)                       \
      if ((m & (J)) == 0) {                             \
        const bool up_ = (UPEXPR);                      \
        u32 x = kv[m], y = kv[m | (J)];                 \
        u32 mn = umin32(x, y), mx = umax32(x, y);       \
        kv[m] = up_ ? mn : mx;                          \
        kv[m | (J)] = up_ ? mx : mn;                    \
      }                                                 \
  }

// async DMA one 8KB input1 row into an LDS buffer (zero VGPR staging).
// LDS dest: wave-uniform base + lane*16 (linear, matches layout); src per-lane.
__device__ __forceinline__ void stage_row(const float* __restrict__ r1,
                                          float* buf, int tid, int w) {
#pragma unroll
  for (int q = 0; q < 4; ++q) {
    const float4* src = (const float4*)r1 + (tid + 128 * q);
    char* dst = (char*)buf + q * 2048 + w * 1024;  // uniform within wave
    __builtin_amdgcn_global_load_lds(
        (const __attribute__((address_space(1))) unsigned int*)src,
        (__attribute__((address_space(3))) unsigned int*)dst, 16, 0, 0);
  }
}

__global__ __launch_bounds__(NT) void listmle_kernel(
    const float* __restrict__ input1,
    const float* __restrict__ input2,
    const int* __restrict__ mask2,
    float* __restrict__ out) {
  __shared__ __align__(16) float rowbuf[N];  // 8KB: channel buf A
  __shared__ __align__(16) u32 slab[N];      // 8KB: keys/exchange, then buf B
  __shared__ float hand[2];  // [0]=wave0 running total, [1]=wave0 partial product

  const int tid = threadIdx.x;
  const int lane = tid & 63;
  const int w = tid >> 6;            // wave within problem (0/1)
  const int p = blockIdx.x;          // p = b*32 + h
  const int b = p >> 5, h = p & 31;
  // global element index: gi = w*1024 + lane*16 + m (m bits0-3, lane bits4-9, w bit10)

  // ---- coalesced input2/mask2 load, build keys, swizzled LDS transpose ----
  // key = fkey(v) top-21 | 11-bit idx (stable-argsort tiebreak);
  // masked -> 0xFFFFF800|idx sorts after all unmasked, ascending idx.
  {
    const float4* i2v = (const float4*)(input2 + (size_t)p * N);
    const int4* m2v = (const int4*)(mask2 + (size_t)p * N);
#pragma unroll
    for (int q = 0; q < 4; ++q) {
      float4 vv = i2v[tid + 128 * q];
      int4 mm = m2v[tid + 128 * q];
      const u32 i0 = 4u * (u32)(tid + 128 * q);
      float vs[4] = {vv.x, vv.y, vv.z, vv.w};
      int ms[4] = {mm.x, mm.y, mm.z, mm.w};
#pragma unroll
      for (int r = 0; r < 4; ++r) {
        u32 idx = i0 + r;
        u32 key = (ms[r] > 0) ? ((fkey(vs[r]) & 0xFFFFF800u) | idx)
                              : (0xFFFFF800u | idx);
        slab[idx ^ ((idx >> 5) & 31u)] = key;  // 2-way worst (free)
      }
    }
  }
  __syncthreads();  // keys visible
  u32 kv[EPK];
#pragma unroll
  for (int m = 0; m < EPK; ++m) {
    u32 idx = (u32)(w * 1024 + lane * EPK + m);
    kv[m] = slab[idx ^ ((idx >> 5) & 31u)];
  }

  // channel-0 row: DMA into rowbuf now; lands during the sort (~3000 cyc cover)
  stage_row(input1 + ((size_t)((b * 4 + 0) * 32 + h)) * N, rowbuf, tid, w);

  // ---- bitonic sort: in-lane + lane-xor passes, 1 cross-wave exchange ----
  INPASS(1, (m & 2) == 0)                                           // k=2
  INPASS(2, (m & 4) == 0) INPASS(1, (m & 4) == 0)                   // k=4
  INPASS(4, (m & 8) == 0) INPASS(2, (m & 8) == 0) INPASS(1, (m & 8) == 0)  // k=8
  {  // k=16 (gi bit4 = lane bit0)
    const bool up = (lane & 1) == 0;
    INPASS(8, up) INPASS(4, up) INPASS(2, up) INPASS(1, up)
  }
  {  // k=32
    const bool up = (lane & 2) == 0;
    sh_pass<1>(kv, ((lane & 1) == 0) == up, lane);
    INPASS(8, up) INPASS(4, up) INPASS(2, up) INPASS(1, up)
  }
  {  // k=64
    const bool up = (lane & 4) == 0;
    sh_pass<2>(kv, ((lane & 2) == 0) == up, lane);
    sh_pass<1>(kv, ((lane & 1) == 0) == up, lane);
    INPASS(8, up) INPASS(4, up) INPASS(2, up) INPASS(1, up)
  }
  {  // k=128
    const bool up = (lane & 8) == 0;
    sh_pass<4>(kv, ((lane & 4) == 0) == up, lane);
    sh_pass<2>(kv, ((lane & 2) == 0) == up, lane);
    sh_pass<1>(kv, ((lane & 1) == 0) == up, lane);
    INPASS(8, up) INPASS(4, up) INPASS(2, up) INPASS(1, up)
  }
  {  // k=256
    const bool up = (lane & 16) == 0;
    sh_pass<8>(kv, ((lane & 8) == 0) == up, lane);
    sh_pass<4>(kv, ((lane & 4) == 0) == up, lane);
    sh_pass<2>(kv, ((lane & 2) == 0) == up, lane);
    sh_pass<1>(kv, ((lane & 1) == 0) == up, lane);
    INPASS(8, up) INPASS(4, up) INPASS(2, up) INPASS(1, up)
  }
  {  // k=512
    const bool up = (lane & 32) == 0;
    sh_pass<16>(kv, ((lane & 16) == 0) == up, lane);
    sh_pass<8>(kv, ((lane & 8) == 0) == up, lane);
    sh_pass<4>(kv, ((lane & 4) == 0) == up, lane);
    sh_pass<2>(kv, ((lane & 2) == 0) == up, lane);
    sh_pass<1>(kv, ((lane & 1) == 0) == up, lane);
    INPASS(8, up) INPASS(4, up) INPASS(2, up) INPASS(1, up)
  }
  {  // k=1024 (gi bit10 = w)
    const bool up = (w == 0);
    sh_pass<32>(kv, ((lane & 32) == 0) == up, lane);
    sh_pass<16>(kv, ((lane & 16) == 0) == up, lane);
    sh_pass<8>(kv, ((lane & 8) == 0) == up, lane);
    sh_pass<4>(kv, ((lane & 4) == 0) == up, lane);
    sh_pass<2>(kv, ((lane & 2) == 0) == up, lane);
    sh_pass<1>(kv, ((lane & 1) == 0) == up, lane);
    INPASS(8, up) INPASS(4, up) INPASS(2, up) INPASS(1, up)
  }
  {  // k=2048: cross-wave exchange at elem-dist 1024 (partner = same lane,m other wave)
    __syncthreads();  // both waves done reading keys slab
#pragma unroll
    for (int m = 0; m < EPK; ++m) slab[w * 1024 + m * 64 + lane] = kv[m];  // conflict-free
    __syncthreads();
#pragma unroll
    for (int m = 0; m < EPK; ++m) {
      u32 o = slab[(w ^ 1) * 1024 + m * 64 + lane];
      kv[m] = (w == 0) ? umin32(kv[m], o) : umax32(kv[m], o);
    }
    __syncthreads();  // exchange reads done before slab reuse as channel buf
    sh_pass<32>(kv, (lane & 32) == 0, lane);
    sh_pass<16>(kv, (lane & 16) == 0, lane);
    sh_pass<8>(kv, (lane & 8) == 0, lane);
    sh_pass<4>(kv, (lane & 4) == 0, lane);
    sh_pass<2>(kv, (lane & 2) == 0, lane);
    sh_pass<1>(kv, (lane & 1) == 0, lane);
    INPASS(8, true) INPASS(4, true) INPASS(2, true) INPASS(1, true)
  }

  // ---- pack sorted (idx, keep): idx bits[0,11), keep at bit 11 ----
  u32 pk[EPK / 2];
#pragma unroll
  for (int t = 0; t < EPK / 2; ++t) {
    u32 a = kv[2 * t], b2 = kv[2 * t + 1];
    u32 ia = (a & 0x7FFu) | ((a < 0xFFFFF800u) ? 0x800u : 0u);
    u32 ib = (b2 & 0x7FFu) | ((b2 < 0xFFFFF800u) ? 0x800u : 0u);
    pk[t] = ia | (ib << 16);
  }

  // ---- channel phase: dbuf rowbuf/slab, async DMA prefetch, 1 full-drain
  //      barrier + 1 raw (vmcnt-preserving) barrier per channel ----
#pragma unroll
  for (int c = 0; c < 4; ++c) {
    float* buf = (c & 1) ? (float*)slab : rowbuf;
    __syncthreads();  // buf's DMA complete (drains vmcnt); prior readers done
    if (c < 3) {      // prefetch next channel into the other buffer
      float* nbuf = (c & 1) ? rowbuf : (float*)slab;
      stage_row(input1 + ((size_t)((b * 4 + c + 1) * 32 + h)) * N, nbuf, tid, w);
    }

    float e[EPK];
    float lsum = 0.f;
#pragma unroll
    for (int m = 0; m < EPK; ++m) {
      u32 info = (pk[m >> 1] >> ((m & 1) * 16)) & 0xFFFFu;
      float v = buf[info & 0x7FFu];  // gather by sorted original index
      float pe = (info & 0x800u) ? __expf(v) : 0.f;
      e[m] = pe;
      lsum += pe;
    }

    // wave-inclusive scan of per-lane sums
    float inc = lsum;
#pragma unroll
    for (int d = 1; d < 64; d <<= 1) {
      float o = __shfl_up(inc, d, 64);
      if (lane >= d) inc += o;
    }
    float excl = inc - lsum;  // exclusive prefix within this wave's half

    if (w == 0) {  // wave0: product of first half; publish total + partial
      float cum = excl;
      float prod = 1.f;
#pragma unroll
      for (int m = 0; m < EPK; ++m) {
        cum += e[m];
        u32 info = pk[m >> 1] >> ((m & 1) * 16);
        if (info & 0x800u) prod *= __fdividef(e[m] + 1e-9f, cum + 1e-9f);
      }
#pragma unroll
      for (int d = 1; d < 64; d <<= 1) prod *= __shfl_xor(prod, d, 64);
      if (lane == 63) hand[0] = inc;   // wave0 total sum
      if (lane == 0) hand[1] = prod;   // wave0 partial product
    }
    // raw barrier: LDS-ordered (lgkmcnt) but does NOT drain vmcnt -> the
    // prefetch DMA stays in flight until the next channel's __syncthreads
    asm volatile("s_waitcnt lgkmcnt(0)" ::: "memory");
    __builtin_amdgcn_s_barrier();
    asm volatile("" ::: "memory");
    if (w == 1) {
      float cum = hand[0] + excl;
      float prod = 1.f;
#pragma unroll
      for (int m = 0; m < EPK; ++m) {
        cum += e[m];
        u32 info = pk[m >> 1] >> ((m & 1) * 16);
        if (info & 0x800u) prod *= __fdividef(e[m] + 1e-9f, cum + 1e-9f);
      }
#pragma unroll
      for (int d = 1; d < 64; d <<= 1) prod *= __shfl_xor(prod, d, 64);
      if (lane == 0) out[(size_t)p * 4 + c] = hand[1] * prod;
    }
  }
}

extern "C" void kernel_launch(void* const* d_in, const int* in_sizes, int n_in,
                              void* d_out, int out_size, void* d_ws, size_t ws_size,
                              hipStream_t stream) {
  const float* input1 = (const float*)d_in[0];
  // d_in[1] = mask1 — unused by the reference forward
  const float* input2 = (const float*)d_in[2];
  const int* mask2 = (const int*)d_in[3];
  float* out = (float*)d_out;

  const int problems = 128 * 32;  // bs * nh; one block (2 waves) per problem
  listmle_kernel<<<problems, NT, 0, stream>>>(input1, input2, mask2, out);
}

// Round 10
// 76.381 us; speedup vs baseline: 1.0561x; 1.0561x over previous
//
#include <hip/hip_runtime.h>

#define N   2048
#define NT  128
#define EPK 16  // 2 waves per problem: 2*64*16 = 2048

typedef unsigned int u32;

// monotone float->uint key: ascending uint order == ascending float order
__device__ __forceinline__ u32 fkey(float f) {
  u32 u = __float_as_uint(f);
  return (u & 0x80000000u) ? ~u : (u | 0x80000000u);
}

__device__ __forceinline__ u32 umin32(u32 a, u32 b) { return a < b ? a : b; }
__device__ __forceinline__ u32 umax32(u32 a, u32 b) { return a < b ? b : a; }

// lane-xor exchange of a u32, cheapest available unit per distance:
//   xor1/xor2: DPP quad_perm (VALU)   xor8: DPP row_ror:8 (rot 8 within 16 == xor8)
//   xor4/xor16: ds_swizzle BitMode    xor32: v_permlane32_swap (gfx950 VALU)
template <int D>
__device__ __forceinline__ u32 exch(u32 x, int lane) {
  if constexpr (D == 1) {
    return (u32)__builtin_amdgcn_update_dpp((int)x, (int)x, 0xB1, 0xF, 0xF, true);
  } else if constexpr (D == 2) {
    return (u32)__builtin_amdgcn_update_dpp((int)x, (int)x, 0x4E, 0xF, 0xF, true);
  } else if constexpr (D == 4) {
    return (u32)__builtin_amdgcn_ds_swizzle((int)x, 0x101F);  // (lane&31)^4
  } else if constexpr (D == 8) {
    return (u32)__builtin_amdgcn_update_dpp((int)x, (int)x, 0x128, 0xF, 0xF, true);
  } else if constexpr (D == 16) {
    return (u32)__builtin_amdgcn_ds_swizzle((int)x, 0x401F);  // (lane&31)^16
  } else {  // D == 32
    int a = (int)x, b = (int)x;
    asm("v_permlane32_swap_b32 %0, %1" : "+v"(a), "+v"(b));
    return (lane & 32) ? (u32)a : (u32)b;
  }
}

// one bitonic pass at lane-distance D (element distance 16*D)
template <int D>
__device__ __forceinline__ void sh_pass(u32* kv, bool keep_min, int lane) {
#pragma unroll
  for (int m = 0; m < EPK; ++m) {
    u32 o = exch<D>(kv[m], lane);
    u32 mn = umin32(kv[m], o), mx = umax32(kv[m], o);
    kv[m] = keep_min ? mn : mx;
  }
}

// in-lane pass at element distance J (<=8)
#define INPASS(J, UPEXPR)                               \
  {                                                     \
    _Pragma("unroll")                                   \
    for (int m = 0; m < EPK; ++m)                       \
      if ((m & (J)) == 0) {                             \
        const bool up_ = (UPEXPR);                      \
        u32 x = kv[m], y = kv[m | (J)];                 \
        u32 mn = umin32(x, y), mx = umax32(x, y);       \
        kv[m] = up_ ? mn : mx;                          \
        kv[m | (J)] = up_ ? mx : mn;                    \
      }                                                 \
  }

// async DMA a full 8KB input1 row into an LDS buffer with ONE wave
// (zero VGPR staging). LDS dest = wave-uniform base + lane*16 (linear).
__device__ __forceinline__ void stage_row_full(const float* __restrict__ r1,
                                               float* buf, int lane) {
#pragma unroll
  for (int q = 0; q < 8; ++q) {
    const float4* src = (const float4*)r1 + (q * 64 + lane);
    char* dst = (char*)buf + q * 1024;  // uniform within wave
    __builtin_amdgcn_global_load_lds(
        (const __attribute__((address_space(1))) unsigned int*)src,
        (__attribute__((address_space(3))) unsigned int*)dst, 16, 0, 0);
  }
}

__global__ __launch_bounds__(NT) void listmle_kernel(
    const float* __restrict__ input1,
    const float* __restrict__ input2,
    const int* __restrict__ mask2,
    float* __restrict__ out) {
  __shared__ __align__(16) u32 slab[N];      // 8KB: keys/exchange/handoff -> wave1 row buf
  __shared__ __align__(16) float rowbuf[N];  // 8KB: wave0 row buf

  const int tid = threadIdx.x;
  const int lane = tid & 63;
  const int w = tid >> 6;            // wave within problem (0/1)
  const int p = blockIdx.x;          // p = b*32 + h
  const int b = p >> 5, h = p & 31;
  // global element index: gi = w*1024 + lane*16 + m (m bits0-3, lane bits4-9, w bit10)

  // ---- coalesced input2/mask2 load, build keys, swizzled LDS transpose ----
  // key = fkey(v) top-21 | 11-bit idx (stable-argsort tiebreak);
  // masked -> 0xFFFFF800|idx sorts after all unmasked, ascending idx.
  {
    const float4* i2v = (const float4*)(input2 + (size_t)p * N);
    const int4* m2v = (const int4*)(mask2 + (size_t)p * N);
#pragma unroll
    for (int q = 0; q < 4; ++q) {
      float4 vv = i2v[tid + 128 * q];
      int4 mm = m2v[tid + 128 * q];
      const u32 i0 = 4u * (u32)(tid + 128 * q);
      float vs[4] = {vv.x, vv.y, vv.z, vv.w};
      int ms[4] = {mm.x, mm.y, mm.z, mm.w};
#pragma unroll
      for (int r = 0; r < 4; ++r) {
        u32 idx = i0 + r;
        u32 key = (ms[r] > 0) ? ((fkey(vs[r]) & 0xFFFFF800u) | idx)
                              : (0xFFFFF800u | idx);
        slab[idx ^ ((idx >> 5) & 31u)] = key;  // 2-way worst (free)
      }
    }
  }

  // wave0's channel-0 row: DMA now; lands during the sort (~6000 cyc cover)
  if (w == 0)
    stage_row_full(input1 + ((size_t)((b * 4 + 0) * 32 + h)) * N, rowbuf, lane);

  __syncthreads();  // keys visible
  u32 kv[EPK];
#pragma unroll
  for (int m = 0; m < EPK; ++m) {
    u32 idx = (u32)(w * 1024 + lane * EPK + m);
    kv[m] = slab[idx ^ ((idx >> 5) & 31u)];
  }

  // ---- bitonic sort: in-lane + lane-xor passes, 1 cross-wave exchange ----
  INPASS(1, (m & 2) == 0)                                           // k=2
  INPASS(2, (m & 4) == 0) INPASS(1, (m & 4) == 0)                   // k=4
  INPASS(4, (m & 8) == 0) INPASS(2, (m & 8) == 0) INPASS(1, (m & 8) == 0)  // k=8
  {  // k=16 (gi bit4 = lane bit0)
    const bool up = (lane & 1) == 0;
    INPASS(8, up) INPASS(4, up) INPASS(2, up) INPASS(1, up)
  }
  {  // k=32
    const bool up = (lane & 2) == 0;
    sh_pass<1>(kv, ((lane & 1) == 0) == up, lane);
    INPASS(8, up) INPASS(4, up) INPASS(2, up) INPASS(1, up)
  }
  {  // k=64
    const bool up = (lane & 4) == 0;
    sh_pass<2>(kv, ((lane & 2) == 0) == up, lane);
    sh_pass<1>(kv, ((lane & 1) == 0) == up, lane);
    INPASS(8, up) INPASS(4, up) INPASS(2, up) INPASS(1, up)
  }
  {  // k=128
    const bool up = (lane & 8) == 0;
    sh_pass<4>(kv, ((lane & 4) == 0) == up, lane);
    sh_pass<2>(kv, ((lane & 2) == 0) == up, lane);
    sh_pass<1>(kv, ((lane & 1) == 0) == up, lane);
    INPASS(8, up) INPASS(4, up) INPASS(2, up) INPASS(1, up)
  }
  {  // k=256
    const bool up = (lane & 16) == 0;
    sh_pass<8>(kv, ((lane & 8) == 0) == up, lane);
    sh_pass<4>(kv, ((lane & 4) == 0) == up, lane);
    sh_pass<2>(kv, ((lane & 2) == 0) == up, lane);
    sh_pass<1>(kv, ((lane & 1) == 0) == up, lane);
    INPASS(8, up) INPASS(4, up) INPASS(2, up) INPASS(1, up)
  }
  {  // k=512
    const bool up = (lane & 32) == 0;
    sh_pass<16>(kv, ((lane & 16) == 0) == up, lane);
    sh_pass<8>(kv, ((lane & 8) == 0) == up, lane);
    sh_pass<4>(kv, ((lane & 4) == 0) == up, lane);
    sh_pass<2>(kv, ((lane & 2) == 0) == up, lane);
    sh_pass<1>(kv, ((lane & 1) == 0) == up, lane);
    INPASS(8, up) INPASS(4, up) INPASS(2, up) INPASS(1, up)
  }
  {  // k=1024 (gi bit10 = w)
    const bool up = (w == 0);
    sh_pass<32>(kv, ((lane & 32) == 0) == up, lane);
    sh_pass<16>(kv, ((lane & 16) == 0) == up, lane);
    sh_pass<8>(kv, ((lane & 8) == 0) == up, lane);
    sh_pass<4>(kv, ((lane & 4) == 0) == up, lane);
    sh_pass<2>(kv, ((lane & 2) == 0) == up, lane);
    sh_pass<1>(kv, ((lane & 1) == 0) == up, lane);
    INPASS(8, up) INPASS(4, up) INPASS(2, up) INPASS(1, up)
  }
  {  // k=2048: cross-wave exchange at elem-dist 1024 (partner = same lane,m other wave)
    __syncthreads();  // both waves done reading keys slab
#pragma unroll
    for (int m = 0; m < EPK; ++m) slab[w * 1024 + m * 64 + lane] = kv[m];  // conflict-free
    __syncthreads();
#pragma unroll
    for (int m = 0; m < EPK; ++m) {
      u32 o = slab[(w ^ 1) * 1024 + m * 64 + lane];
      kv[m] = (w == 0) ? umin32(kv[m], o) : umax32(kv[m], o);
    }
    __syncthreads();  // exchange reads done before slab reuse (handoff)
    sh_pass<32>(kv, (lane & 32) == 0, lane);
    sh_pass<16>(kv, (lane & 16) == 0, lane);
    sh_pass<8>(kv, (lane & 8) == 0, lane);
    sh_pass<4>(kv, (lane & 4) == 0, lane);
    sh_pass<2>(kv, (lane & 2) == 0, lane);
    sh_pass<1>(kv, (lane & 1) == 0, lane);
    INPASS(8, true) INPASS(4, true) INPASS(2, true) INPASS(1, true)
  }

  // ---- handoff: both halves -> LDS as packed u16 (idx | keep<<11); each
  //      wave reads back the FULL sorted list (32 entries = 16 u32 per lane) ----
  {
    u32* pairs = slab;  // 1024 u32 = 4KB
#pragma unroll
    for (int t = 0; t < EPK / 2; ++t) {
      u32 a = kv[2 * t], b2 = kv[2 * t + 1];
      u32 ia = (a & 0x7FFu) | ((a < 0xFFFFF800u) ? 0x800u : 0u);
      u32 ib = (b2 & 0x7FFu) | ((b2 < 0xFFFFF800u) ? 0x800u : 0u);
      u32 slot = (u32)(w * 512 + lane * 8 + t);
      pairs[slot ^ ((slot >> 5) & 31u)] = ia | (ib << 16);  // ~2-way
    }
  }
  __syncthreads();  // handoff visible
  u32 pk[EPK];      // 16 u32 = full list's 32 entries for this lane
#pragma unroll
  for (int t = 0; t < EPK; ++t) {
    u32 slot = (u32)(lane * 16 + t);
    pk[t] = slab[slot ^ ((slot >> 5) & 31u)];
  }
  __syncthreads();  // all reads done -> slab becomes wave1's row buffer

  // wave1's channel-2 row: DMA now (covered by other resident waves)
  if (w == 1)
    stage_row_full(input1 + ((size_t)((b * 4 + 2) * 32 + h)) * N, (float*)slab, lane);

  // ---- channel phase: wave w owns channels {2w, 2w+1} and its private
  //      buffer. NO barriers from here on: waves drift independently. ----
  float* mybuf = (w == 0) ? rowbuf : (float*)slab;
#pragma unroll
  for (int cc = 0; cc < 2; ++cc) {
    const int c = 2 * w + cc;
    asm volatile("s_waitcnt vmcnt(0)" ::: "memory");  // my row DMA landed

    float e[32];
    float lsum = 0.f;
#pragma unroll
    for (int m = 0; m < 32; ++m) {
      u32 info = (pk[m >> 1] >> ((m & 1) * 16)) & 0xFFFFu;
      float v = mybuf[info & 0x7FFu];  // gather by sorted original index
      float pe = (info & 0x800u) ? __expf(v) : 0.f;
      e[m] = pe;
      lsum += pe;
    }

    if (cc == 0) {  // gathers done -> safe to DMA next channel into same buf
      asm volatile("s_waitcnt lgkmcnt(0)" ::: "memory");
      stage_row_full(input1 + ((size_t)((b * 4 + c + 1) * 32 + h)) * N, mybuf, lane);
    }

    // wave scan over the full row (lane order == sorted order, 32 elems/lane)
    float inc = lsum;
#pragma unroll
    for (int d = 1; d < 64; d <<= 1) {
      float o = __shfl_up(inc, d, 64);
      if (lane >= d) inc += o;
    }
    float cum = inc - lsum;  // exclusive prefix

    float prod = 1.f;
#pragma unroll
    for (int m = 0; m < 32; ++m) {
      cum += e[m];
      u32 info = pk[m >> 1] >> ((m & 1) * 16);
      if (info & 0x800u) prod *= __fdividef(e[m] + 1e-9f, cum + 1e-9f);
    }
#pragma unroll
    for (int d = 1; d < 64; d <<= 1) prod *= __shfl_xor(prod, d, 64);
    if (lane == 0) out[(size_t)p * 4 + c] = prod;
  }
}

extern "C" void kernel_launch(void* const* d_in, const int* in_sizes, int n_in,
                              void* d_out, int out_size, void* d_ws, size_t ws_size,
                              hipStream_t stream) {
  const float* input1 = (const float*)d_in[0];
  // d_in[1] = mask1 — unused by the reference forward
  const float* input2 = (const float*)d_in[2];
  const int* mask2 = (const int*)d_in[3];
  float* out = (float*)d_out;

  const int problems = 128 * 32;  // bs * nh; one block (2 waves) per problem
  listmle_kernel<<<problems, NT, 0, stream>>>(input1, input2, mask2, out);
}